// Round 6
// baseline (1313.700 us; speedup 1.0000x reference)
//
#include <hip/hip_runtime.h>
#include <hip/hip_bf16.h>

// db4 synthesis filters. g1[j] = (-1)^j * g0[7-j].
__device__ constexpr float G0[8] = {
    0.23037781330885523f,  0.7148465705525415f,  0.6308807679295904f,  -0.02798376941698385f,
    -0.18703481171888114f, 0.030841381835986965f, 0.032883011666982945f, -0.010597401784997278f};
__device__ constexpr float G1[8] = {
    -0.010597401784997278f, -0.032883011666982945f, 0.030841381835986965f, 0.18703481171888114f,
    -0.02798376941698385f,  -0.6308807679295904f,   0.7148465705525415f,  -0.23037781330885523f};

// One level of 3D inverse db4 DWT as a direct gather (tensor-product expansion).
// low:(16,n,n,n) highs:(16,7,n,n,n) -> out:(16,N,N,N), N=2n-6.
// out[gz][gy][gx] = sum_{band} sum_{mz,my,mx in 0..3}
//     src_band[(gz>>1)+3-mz][(gy>>1)+3-my][(gx>>1)+3-mx]
//     * Wz[(gz&1)+2mz] * Wy[(gy&1)+2my] * Wx[(gx&1)+2mx]
// where W* = G1 if the band's bit for that axis is set else G0 (bit0=x,bit1=y,bit2=z).
// Indices provably in-bounds: (g>>1)+3-m in [g>>1, g>>1+3], max = ((N-1)>>1)+3 = n-1.
// Each thread computes the two x-parity outputs (2*ux, 2*ux+1), which share all rows.
__global__ __launch_bounds__(256) void idwt3_gather(const float* __restrict__ low,
                                                    const float* __restrict__ highs,
                                                    float* __restrict__ out,
                                                    int n, int N) {
  const int b = blockIdx.y;
  const long n3 = (long)n * n * n;
  const int H = N >> 1;                    // x-pairs per row
  const int npairs = H * N * N;            // per-volume thread count
  const int q = blockIdx.x * 256 + threadIdx.x;
  if (q >= npairs) return;
  const int ux = q % H;
  const int gy = (q / H) % N;
  const int gz = q / (H * N);
  const int xb = ux, yb = gy >> 1, zb = gz >> 1;
  const int py = gy & 1, pz = gz & 1;

  // per-axis tap weights: [g0_or_g1][m]
  float zw[2][4], yw[2][4], xw0[2][4], xw1[2][4];
#pragma unroll
  for (int m = 0; m < 4; ++m) {
    zw[0][m] = G0[pz + 2 * m];  zw[1][m] = G1[pz + 2 * m];
    yw[0][m] = G0[py + 2 * m];  yw[1][m] = G1[py + 2 * m];
    xw0[0][m] = G0[2 * m];      xw0[1][m] = G1[2 * m];       // gx even
    xw1[0][m] = G0[2 * m + 1];  xw1[1][m] = G1[2 * m + 1];   // gx odd
  }

  float acc0 = 0.0f, acc1 = 0.0f;
#pragma unroll
  for (int band = 0; band < 8; ++band) {
    const float* src = (band == 0) ? (low + (long)b * n3)
                                   : (highs + ((long)b * 7 + (band - 1)) * n3);
    const int sx = band & 1, sy = (band >> 1) & 1, sz = band >> 2;
    float a0 = 0.0f, a1 = 0.0f;
#pragma unroll
    for (int mz = 0; mz < 4; ++mz) {
#pragma unroll
      for (int my = 0; my < 4; ++my) {
        const float* row = src + ((long)(zb + 3 - mz) * n + (yb + 3 - my)) * n + xb;
        const float r0 = row[0], r1 = row[1], r2 = row[2], r3 = row[3];
        // x-dot: input idx xb+3-mx pairs with Wx[px+2mx]  ->  row[3-mx] * xw[mx]
        const float d0 = r3 * xw0[sx][0] + r2 * xw0[sx][1] + r1 * xw0[sx][2] + r0 * xw0[sx][3];
        const float d1 = r3 * xw1[sx][0] + r2 * xw1[sx][1] + r1 * xw1[sx][2] + r0 * xw1[sx][3];
        const float c = zw[sz][mz] * yw[sy][my];
        a0 = fmaf(d0, c, a0);
        a1 = fmaf(d1, c, a1);
      }
    }
    acc0 += a0;
    acc1 += a1;
  }

  const long N3 = (long)N * N * N;
  const long o = (long)b * N3 + ((long)gz * N + gy) * N + 2 * ux;
  out[o] = acc0;
  out[o + 1] = acc1;
}

extern "C" void kernel_launch(void* const* d_in, const int* in_sizes, int n_in,
                              void* d_out, int out_size, void* d_ws, size_t ws_size,
                              hipStream_t stream) {
  // Identify inputs BY SIZE (element counts — confirmed R5):
  //   yl  (2,8,36^3)    =   746,496
  //   yh0 (2,8,7,66^3)  = 32,199,552
  //   yh1 (2,8,7,36^3)  =  5,225,472
  const float* yl  = nullptr;
  const float* yh0 = nullptr;
  const float* yh1 = nullptr;
  for (int i = 0; i < n_in; ++i) {
    if (in_sizes[i] == 746496)        yl  = (const float*)d_in[i];
    else if (in_sizes[i] == 32199552) yh0 = (const float*)d_in[i];
    else if (in_sizes[i] == 5225472)  yh1 = (const float*)d_in[i];
  }
  if (!yl || !yh0 || !yh1) {
    yl  = (const float*)d_in[0];
    yh0 = (const float*)d_in[1];
    yh1 = (const float*)d_in[2];
  }
  // Reference returns jnp.float32 -> output buffer is fp32 (the "bf16" in the test
  // label is the tolerance regime, not storage; R3/R4/R5's 7.6875 = sqrt(2)*5.5
  // proved the buffer was being read as fp32 while we packed bf16).
  float* out = (float*)d_out;

  float* ll = (float*)d_ws;  // (16,66^3) fp32 = 18.4 MB inter-level buffer

  // Level 1: (36 -> 66), highs = yh1. pairs/volume = 33*66*66 = 143748 -> 562 blocks.
  idwt3_gather<<<dim3(562, 16), 256, 0, stream>>>(yl, yh1, ll, 36, 66);

  // Level 2: (66 -> 126), highs = yh0. pairs/volume = 63*126*126 = 1000188 -> 3907 blocks.
  idwt3_gather<<<dim3(3907, 16), 256, 0, stream>>>(ll, yh0, out, 66, 126);
}